// Round 1
// 565.951 us; speedup vs baseline: 1.0161x; 1.0161x over previous
//
#include <hip/hip_runtime.h>
#include <math.h>

// ---------------- problem constants ----------------
#define TSTEPS 40
#define GATED  30
#define BATCH  4096
#define XD     150
#define HD     150
#define HP     160      // padded hidden/x dim
#define PITCHW 328      // Wc row pitch (bf16 elems, 656 B)
#define SXP    328      // sxh row pitch (bf16 elems)
#define WROWS  704      // 640 gate rows + 64 w1 rows
#define SGP    643      // sg pitch (fp32)
#define ROWS   16       // batch rows per block (MFMA M)
#define NT     512      // 8 waves
#define NBLK   (BATCH / ROWS)  // 256 blocks -> 1 per CU

// post-pass chunking
#define TCH    4        // timesteps per post-pass chunk
#define S1P    66       // st1p pitch (fp32)
#define S2P    27       // st2p pitch (fp32)

// output packing (flat fp32)
#define OFF_OUTPUTS 614400
#define OFF_YS      25190400

typedef float  floatx4 __attribute__((ext_vector_type(4)));
typedef short  shortx8 __attribute__((ext_vector_type(8)));

__device__ __forceinline__ unsigned short bf16_rne(float f) {
    union { float f; unsigned int u; } v; v.f = f;
    unsigned int u = v.u;
    return (unsigned short)((u + 0x7fffu + ((u >> 16) & 1u)) >> 16);
}
__device__ __forceinline__ unsigned int pk2bf(float a, float b) {
    return (unsigned int)bf16_rne(a) | ((unsigned int)bf16_rne(b) << 16);
}
__device__ __forceinline__ float sigf(float x) {
    return 1.0f / (1.0f + __expf(-x));
}
__device__ __forceinline__ float tanh_fast(float x) {
    x = fminf(fmaxf(x, -15.0f), 15.0f);
    float t = __expf(2.0f * x);
    return (t - 1.0f) / (t + 1.0f);
}

// ---------------- weight packing (unchanged) ----------------
__global__ void pack_weights(const float* __restrict__ w_ih, const float* __restrict__ w_hh,
                             const float* __restrict__ b_ih, const float* __restrict__ b_hh,
                             const float* __restrict__ w1,
                             unsigned short* __restrict__ Wc, float* __restrict__ bcp) {
    int idx = blockIdx.x * blockDim.x + threadIdx.x;
    int stride = gridDim.x * blockDim.x;
    for (int i = idx; i < WROWS * PITCHW; i += stride) {
        int j = i / PITCHW, k = i - j * PITCHW;
        float v = 0.0f;
        if (j < 640) {
            int tp = j / HP, u = j - tp * HP;
            if (u < 150) {
                int src = tp * 150 + u;
                if (k < 150)                    v = w_ih[src * 150 + k];
                else if (k >= 160 && k < 310)   v = w_hh[src * 150 + (k - 160)];
            }
        } else {
            int j1 = j - 640;
            if (j1 < 50) {
                if (k < 150)                    v = w1[j1 * 300 + 150 + k];   // x part
                else if (k >= 160 && k < 310)   v = w1[j1 * 300 + (k - 160)]; // h part
            }
        }
        Wc[i] = bf16_rne(v);
    }
    for (int i = idx; i < 640; i += stride) {
        int tp = i / HP, u = i - tp * HP;
        bcp[i] = (u < 150) ? (b_ih[tp * 150 + u] + b_hh[tp * 150 + u]) : 0.0f;
    }
}

// ---------------- main persistent LSTM kernel ----------------
// Loop structure (2 barriers/step, uniform for all 40 steps):
//   [prefetch x_{t+1} -> regs] [gate MFMA from sxh] -> sg
//   B2
//   [pointwise cell update -> h into sxh h-part; x_{t+1} regs -> sxh x-part; outputs]
//   B3
// Stop-gate MLP (ys) is deferred to a fully parallel post-pass reading x + outputs.
__global__ __launch_bounds__(NT, 2)
void lstm_main(const float* __restrict__ x,
               const unsigned short* __restrict__ Wc,
               const float* __restrict__ bcp, const float* __restrict__ b1,
               const float* __restrict__ w2, const float* __restrict__ b2,
               const float* __restrict__ w3, const float* __restrict__ b3,
               float* __restrict__ outh, float* __restrict__ outputs,
               float* __restrict__ ys) {
    __shared__ unsigned short sxh[ROWS][SXP];      // bf16 [x(0..149)|0|h(160..309)|0]
    __shared__ float sg[ROWS][SGP];                // gate pre-activations (640 used)
    __shared__ unsigned short stage4[TCH * 16][SXP]; // post-pass [x|h] staging (4 steps)
    __shared__ float st1p[TCH * 16][S1P];          // post-pass layer1 out
    __shared__ float st2p[TCH * 16][S2P];          // post-pass layer2 out
    __shared__ float bcs[640], b1s[64];
    __shared__ float sw2[1250], sb2[25], sw3[50], sb3[2];

    const int tid  = threadIdx.x;
    const int lane = tid & 63;
    const int wv   = tid >> 6;     // wave 0..7
    const int lrow = lane & 15;    // tile row
    const int lq   = lane >> 4;    // quad 0..3
    const int row0 = blockIdx.x * ROWS;

    // ---- one-time init ----
    for (int i = tid; i < ROWS * SXP; i += NT) {
        int r = i / SXP, k = i - r * SXP;
        if (k >= 150) sxh[r][k] = 0;   // h=0, pads=0
    }
    for (int i = tid; i < TCH * 16 * SXP; i += NT)
        ((unsigned short*)stage4)[i] = 0;          // pads stay 0 across all chunks
    // stage x_0
    for (int i = tid; i < ROWS * 75; i += NT) {
        int rr = i / 75, kk = i - rr * 75;
        float2 v = *(const float2*)(x + ((size_t)row0 + rr) * XD + 2 * kk);
        *(unsigned int*)&sxh[rr][2 * kk] = pk2bf(v.x, v.y);
    }
    for (int i = tid; i < 640; i += NT) bcs[i] = bcp[i];
    if (tid < 64) b1s[tid] = (tid < 50) ? b1[tid] : 0.0f;
    for (int i = tid; i < 1250; i += NT) sw2[i] = w2[i];
    if (tid < 25) sb2[tid] = b2[tid];
    if (tid < 50) sw3[tid] = w3[tid];
    if (tid < 2)  sb3[tid] = b3[tid];

    // ---- load this wave's 5 gate tiles into registers (stay for all 40 steps) ----
    shortx8 bfr[50];
#pragma unroll
    for (int it = 0; it < 5; ++it) {
        const unsigned short* wp =
            Wc + (size_t)((wv + 8 * it) * 16 + lrow) * PITCHW + lq * 8;
#pragma unroll
        for (int kb = 0; kb < 10; ++kb)
            bfr[it * 10 + kb] = *(const shortx8*)(wp + kb * 32);
    }

    float creg[5];
#pragma unroll
    for (int p = 0; p < 5; ++p) creg[p] = 0.0f;

    __syncthreads();

    // =================== recurrent loop ===================
    for (int t = 0; t < TSTEPS; ++t) {
        // ---- prefetch x_{t+1} into registers (hidden under MFMA phase) ----
        float2 px0, px1, px2;
        const bool pf = (t + 1 < TSTEPS);
        if (pf) {
            const float* xn = x + ((size_t)(t + 1) * BATCH + row0) * XD;
            { int i = tid;          px0 = *(const float2*)(xn + (i / 75) * XD + 2 * (i % 75)); }
            { int i = tid + NT;     px1 = *(const float2*)(xn + (i / 75) * XD + 2 * (i % 75)); }
            if (tid + 2 * NT < ROWS * 75) {
                int i = tid + 2 * NT;
                px2 = *(const float2*)(xn + (i / 75) * XD + 2 * (i % 75));
            }
        }

        // ---- gate MFMAs: kb-outer, weights from registers ----
        {
            floatx4 acc[5];
#pragma unroll
            for (int it = 0; it < 5; ++it) acc[it] = (floatx4){0.f, 0.f, 0.f, 0.f};
#pragma unroll
            for (int kb = 0; kb < 10; ++kb) {
                shortx8 a = *(const shortx8*)&sxh[lrow][kb * 32 + lq * 8];
#pragma unroll
                for (int it = 0; it < 5; ++it)
                    acc[it] = __builtin_amdgcn_mfma_f32_16x16x32_bf16(
                        a, bfr[it * 10 + kb], acc[it], 0, 0, 0);
            }
#pragma unroll
            for (int it = 0; it < 5; ++it) {
                const int colb = (wv + 8 * it) * 16 + lrow;
#pragma unroll
                for (int rg = 0; rg < 4; ++rg)
                    sg[lq * 4 + rg][colb] = acc[it][rg];
            }
        }
        __syncthreads();   // B2: sg ready; all sxh reads done -> safe to overwrite sxh

        // ---- pointwise cell update (i,f,g,o); h -> sxh + outputs; x_{t+1} -> sxh ----
#pragma unroll
        for (int p = 0; p < 5; ++p) {
            int e = tid + NT * p;
            int r = e / HP, u = e - r * HP;
            float gi = sg[r][u]          + bcs[u];
            float gf = sg[r][HP + u]     + bcs[HP + u];
            float gg = sg[r][2 * HP + u] + bcs[2 * HP + u];
            float go = sg[r][3 * HP + u] + bcs[3 * HP + u];
            float cn = sigf(gf) * creg[p] + sigf(gi) * tanh_fast(gg);
            creg[p] = cn;
            float h = sigf(go) * tanh_fast(cn);
            sxh[r][HP + u] = bf16_rne(h);
            if (u < 150) {
                outputs[((size_t)t * BATCH + row0 + r) * HD + u] = h;
                if (t == GATED - 1)
                    outh[(size_t)(row0 + r) * HD + u] = h;
            }
        }
        if (pf) {
            { int i = tid;      *(unsigned int*)&sxh[i / 75][2 * (i % 75)] = pk2bf(px0.x, px0.y); }
            { int i = tid + NT; *(unsigned int*)&sxh[i / 75][2 * (i % 75)] = pk2bf(px1.x, px1.y); }
            if (tid + 2 * NT < ROWS * 75) {
                int i = tid + 2 * NT;
                *(unsigned int*)&sxh[i / 75][2 * (i % 75)] = pk2bf(px2.x, px2.y);
            }
        }
        __syncthreads();   // B3: new h + x_{t+1} in sxh
    }

    // =================== post-pass: stop-gate MLP for t < GATED ===================
    // Fully parallel over (t, row); reads x (input) and outputs (our own rows, L2/L3-hot).
    for (int t0 = 0; t0 < GATED; t0 += TCH) {
        const int tcur = (GATED - t0 < TCH) ? (GATED - t0) : TCH;

        // ---- stage [x_t | h_t] as bf16 into stage4 (pads already 0) ----
        for (int i = tid; i < tcur * 16 * 75; i += NT) {
            int row = i / 75, kk = i - row * 75;
            int r = row & 15, tl = row >> 4;
            size_t base = ((size_t)(t0 + tl) * BATCH + row0 + r) * (size_t)XD;
            float2 xv = *(const float2*)(x + base + 2 * kk);
            float2 hv = *(const float2*)(outputs + base + 2 * kk);   // HD==XD
            *(unsigned int*)&stage4[row][2 * kk]      = pk2bf(xv.x, xv.y);
            *(unsigned int*)&stage4[row][HP + 2 * kk] = pk2bf(hv.x, hv.y);
        }
        __syncthreads();

        // ---- w1 MFMAs: 16 jobs (tl, ct), 2 per wave, full K=320 each ----
#pragma unroll
        for (int jj = 0; jj < 2; ++jj) {
            int job = wv * 2 + jj;            // 0..15
            int tl = job >> 2, ct = job & 3;
            if (tl < tcur) {
                const unsigned short* wp1 =
                    Wc + (size_t)(640 + ct * 16 + lrow) * PITCHW + lq * 8;
                floatx4 aw = {0.f, 0.f, 0.f, 0.f};
#pragma unroll
                for (int kb = 0; kb < 10; ++kb) {
                    shortx8 a = *(const shortx8*)&stage4[tl * 16 + lrow][kb * 32 + lq * 8];
                    shortx8 b = *(const shortx8*)(wp1 + kb * 32);
                    aw = __builtin_amdgcn_mfma_f32_16x16x32_bf16(a, b, aw, 0, 0, 0);
                }
#pragma unroll
                for (int rg = 0; rg < 4; ++rg)
                    st1p[tl * 16 + lq * 4 + rg][ct * 16 + lrow] = aw[rg];
            }
        }
        __syncthreads();

        // ---- layer1 bias + relu (in place) ----
        for (int e = tid; e < tcur * 16 * 64; e += NT) {
            int s = e >> 6, j = e & 63;
            float v = st1p[s][j] + b1s[j];
            st1p[s][j] = v > 0.0f ? v : 0.0f;
        }
        __syncthreads();

        // ---- layer2: dot-50 + relu ----
        for (int u = tid; u < tcur * 16 * 25; u += NT) {
            int s = u / 25, j = u - s * 25;
            float a = sb2[j];
            const float* w2r = &sw2[j * 50];
#pragma unroll 10
            for (int k2 = 0; k2 < 50; ++k2)
                a = fmaf(w2r[k2], st1p[s][k2], a);
            st2p[s][j] = a > 0.0f ? a : 0.0f;
        }
        __syncthreads();

        // ---- layer3 + relu + softmax(2) ----
        if (tid < tcur * 16) {
            int tl = tid >> 4, r = tid & 15;
            float z0 = sb3[0], z1 = sb3[1];
#pragma unroll
            for (int k2 = 0; k2 < 25; ++k2) {
                z0 = fmaf(sw3[k2],      st2p[tid][k2], z0);
                z1 = fmaf(sw3[25 + k2], st2p[tid][k2], z1);
            }
            z0 = z0 > 0.0f ? z0 : 0.0f;
            z1 = z1 > 0.0f ? z1 : 0.0f;
            float mx = fmaxf(z0, z1);
            float e0 = __expf(z0 - mx), e1 = __expf(z1 - mx);
            float inv = 1.0f / (e0 + e1);
            size_t yb = ((size_t)(t0 + tl) * BATCH + row0 + r) * 2;
            ys[yb]     = e0 * inv;
            ys[yb + 1] = e1 * inv;
        }
        __syncthreads();   // protect stage4/st1p/st2p before next chunk
    }
}

extern "C" void kernel_launch(void* const* d_in, const int* in_sizes, int n_in,
                              void* d_out, int out_size, void* d_ws, size_t ws_size,
                              hipStream_t stream) {
    const float* x    = (const float*)d_in[0];
    const float* w_ih = (const float*)d_in[1];
    const float* w_hh = (const float*)d_in[2];
    const float* b_ih = (const float*)d_in[3];
    const float* b_hh = (const float*)d_in[4];
    const float* w1   = (const float*)d_in[5];
    const float* b1   = (const float*)d_in[6];
    const float* w2   = (const float*)d_in[7];
    const float* b2   = (const float*)d_in[8];
    const float* w3   = (const float*)d_in[9];
    const float* b3   = (const float*)d_in[10];

    float* out = (float*)d_out;
    unsigned short* Wc  = (unsigned short*)d_ws;           // 704*328 bf16
    float*          bcp = (float*)(Wc + WROWS * PITCHW);   // 640

    pack_weights<<<256, 256, 0, stream>>>(w_ih, w_hh, b_ih, b_hh, w1, Wc, bcp);

    lstm_main<<<NBLK, NT, 0, stream>>>(
        x, Wc, bcp, b1, w2, b2, w3, b3,
        out, out + OFF_OUTPUTS, out + OFF_YS);
}

// Round 2
// 402.424 us; speedup vs baseline: 1.4289x; 1.4064x over previous
//
#include <hip/hip_runtime.h>
#include <math.h>

// ---------------- problem constants ----------------
#define TSTEPS 40
#define GATED  30
#define BATCH  4096
#define XD     150
#define HD     150
#define HP     160      // padded hidden/x dim
#define PITCHW 328      // Wc row pitch (bf16 elems, 656 B)
#define SXP    328      // sxh row pitch (bf16 elems)
#define WROWS  704      // 640 gate rows + 64 w1 rows
#define SGP    643      // sg pitch (fp32)
#define ROWS   16       // batch rows per block (MFMA M)
#define NT     512      // 8 waves
#define NBLK   (BATCH / ROWS)  // 256 blocks -> 1 per CU

// post-pass chunking
#define TCH    4        // timesteps per post-pass chunk
#define S1P    66       // st1p pitch (fp32)
#define S2P    27       // st2p pitch (fp32)

// output packing (flat fp32)
#define OFF_OUTPUTS 614400
#define OFF_YS      25190400

typedef float  floatx4 __attribute__((ext_vector_type(4)));
typedef short  shortx8 __attribute__((ext_vector_type(8)));

__device__ __forceinline__ unsigned short bf16_rne(float f) {
    union { float f; unsigned int u; } v; v.f = f;
    unsigned int u = v.u;
    return (unsigned short)((u + 0x7fffu + ((u >> 16) & 1u)) >> 16);
}
__device__ __forceinline__ unsigned int pk2bf(float a, float b) {
    return (unsigned int)bf16_rne(a) | ((unsigned int)bf16_rne(b) << 16);
}
__device__ __forceinline__ float sigf(float x) {
    return 1.0f / (1.0f + __expf(-x));
}
__device__ __forceinline__ float tanh_fast(float x) {
    x = fminf(fmaxf(x, -15.0f), 15.0f);
    float t = __expf(2.0f * x);
    return (t - 1.0f) / (t + 1.0f);
}

// ---------------- weight packing (unchanged) ----------------
__global__ void pack_weights(const float* __restrict__ w_ih, const float* __restrict__ w_hh,
                             const float* __restrict__ b_ih, const float* __restrict__ b_hh,
                             const float* __restrict__ w1,
                             unsigned short* __restrict__ Wc, float* __restrict__ bcp) {
    int idx = blockIdx.x * blockDim.x + threadIdx.x;
    int stride = gridDim.x * blockDim.x;
    for (int i = idx; i < WROWS * PITCHW; i += stride) {
        int j = i / PITCHW, k = i - j * PITCHW;
        float v = 0.0f;
        if (j < 640) {
            int tp = j / HP, u = j - tp * HP;
            if (u < 150) {
                int src = tp * 150 + u;
                if (k < 150)                    v = w_ih[src * 150 + k];
                else if (k >= 160 && k < 310)   v = w_hh[src * 150 + (k - 160)];
            }
        } else {
            int j1 = j - 640;
            if (j1 < 50) {
                if (k < 150)                    v = w1[j1 * 300 + 150 + k];   // x part
                else if (k >= 160 && k < 310)   v = w1[j1 * 300 + (k - 160)]; // h part
            }
        }
        Wc[i] = bf16_rne(v);
    }
    for (int i = idx; i < 640; i += stride) {
        int tp = i / HP, u = i - tp * HP;
        bcp[i] = (u < 150) ? (b_ih[tp * 150 + u] + b_hh[tp * 150 + u]) : 0.0f;
    }
}

// ---------------- main persistent LSTM kernel ----------------
// Register budget fix: each wave keeps 4 of its 5 gate tiles in registers
// (bfr[40] = 160 VGPRs) and reads the 5th (tile wv+32) from LDS (wlds),
// so NOTHING spills. Weights are fully CU-resident: 328 KB regs + 84 KB LDS.
__global__ __launch_bounds__(NT, 2)
void lstm_main(const float* __restrict__ x,
               const unsigned short* __restrict__ Wc,
               const float* __restrict__ bcp, const float* __restrict__ b1,
               const float* __restrict__ w2, const float* __restrict__ b2,
               const float* __restrict__ w3, const float* __restrict__ b3,
               float* __restrict__ outh, float* __restrict__ outputs,
               float* __restrict__ ys) {
    __shared__ unsigned short sxh[ROWS][SXP];      // bf16 [x(0..149)|0|h(160..309)|0]
    __shared__ float sg[ROWS][SGP];                // gate pre-activations (640 used)
    __shared__ unsigned short wlds[8][16][SXP];    // gate tiles 32..39 (84 KB)
    __shared__ float bcs[640], b1s[64];
    __shared__ float sw2[1250], sb2[25], sw3[50], sb3[2];

    // post-pass arrays aliased into wlds (dead after recurrent loop):
    // stage4: 4*16*328 shorts = 41984 B; st1p: 64*66 f32 = 16896 B; st2p: 64*27 f32
    unsigned short (*stage4)[SXP] = (unsigned short(*)[SXP])&wlds[0][0][0];
    float (*st1p)[S1P] = (float(*)[S1P])((char*)&wlds[0][0][0] + 41984);
    float (*st2p)[S2P] = (float(*)[S2P])((char*)&wlds[0][0][0] + 58880);

    const int tid  = threadIdx.x;
    const int lane = tid & 63;
    const int wv   = tid >> 6;     // wave 0..7
    const int lrow = lane & 15;    // tile row
    const int lq   = lane >> 4;    // quad 0..3
    const int row0 = blockIdx.x * ROWS;

    // ---- one-time init ----
    for (int i = tid; i < ROWS * SXP; i += NT) {
        int r = i / SXP, k = i - r * SXP;
        if (k >= 150) sxh[r][k] = 0;   // h=0, pads=0
    }
    // stage x_0
    for (int i = tid; i < ROWS * 75; i += NT) {
        int rr = i / 75, kk = i - rr * 75;
        float2 v = *(const float2*)(x + ((size_t)row0 + rr) * XD + 2 * kk);
        *(unsigned int*)&sxh[rr][2 * kk] = pk2bf(v.x, v.y);
    }
    // copy gate tiles 32..39 into LDS (cols 0..319; pads never read)
    for (int i = tid; i < 8 * 16 * 160; i += NT) {
        int w = i / (16 * 160);
        int rem = i - w * (16 * 160);
        int r = rem / 160, k = rem - r * 160;   // k counts uint pairs
        *(unsigned int*)&wlds[w][r][2 * k] =
            *(const unsigned int*)&Wc[(size_t)((32 + w) * 16 + r) * PITCHW + 2 * k];
    }
    for (int i = tid; i < 640; i += NT) bcs[i] = bcp[i];
    if (tid < 64) b1s[tid] = (tid < 50) ? b1[tid] : 0.0f;
    for (int i = tid; i < 1250; i += NT) sw2[i] = w2[i];
    if (tid < 25) sb2[tid] = b2[tid];
    if (tid < 50) sw3[tid] = w3[tid];
    if (tid < 2)  sb3[tid] = b3[tid];

    // ---- load this wave's 4 register-resident gate tiles (tiles wv+8*it, it<4) ----
    shortx8 bfr[40];
#pragma unroll
    for (int it = 0; it < 4; ++it) {
        const unsigned short* wp =
            Wc + (size_t)((wv + 8 * it) * 16 + lrow) * PITCHW + lq * 8;
#pragma unroll
        for (int kb = 0; kb < 10; ++kb)
            bfr[it * 10 + kb] = *(const shortx8*)(wp + kb * 32);
    }

    float creg[5];
#pragma unroll
    for (int p = 0; p < 5; ++p) creg[p] = 0.0f;

    __syncthreads();

    // =================== recurrent loop (2 barriers/step) ===================
    for (int t = 0; t < TSTEPS; ++t) {
        // ---- prefetch x_{t+1} into registers (hidden under MFMA phase) ----
        float2 px0, px1, px2;
        const bool pf = (t + 1 < TSTEPS);
        if (pf) {
            const float* xn = x + ((size_t)(t + 1) * BATCH + row0) * XD;
            { int i = tid;          px0 = *(const float2*)(xn + (i / 75) * XD + 2 * (i % 75)); }
            { int i = tid + NT;     px1 = *(const float2*)(xn + (i / 75) * XD + 2 * (i % 75)); }
            if (tid + 2 * NT < ROWS * 75) {
                int i = tid + 2 * NT;
                px2 = *(const float2*)(xn + (i / 75) * XD + 2 * (i % 75));
            }
        }

        // ---- gate MFMAs: 4 tiles from registers + 1 tile from LDS ----
        {
            floatx4 acc[5];
#pragma unroll
            for (int it = 0; it < 5; ++it) acc[it] = (floatx4){0.f, 0.f, 0.f, 0.f};
#pragma unroll
            for (int kb = 0; kb < 10; ++kb) {
                shortx8 a = *(const shortx8*)&sxh[lrow][kb * 32 + lq * 8];
#pragma unroll
                for (int it = 0; it < 4; ++it)
                    acc[it] = __builtin_amdgcn_mfma_f32_16x16x32_bf16(
                        a, bfr[it * 10 + kb], acc[it], 0, 0, 0);
                shortx8 b4 = *(const shortx8*)&wlds[wv][lrow][kb * 32 + lq * 8];
                acc[4] = __builtin_amdgcn_mfma_f32_16x16x32_bf16(a, b4, acc[4], 0, 0, 0);
            }
#pragma unroll
            for (int it = 0; it < 5; ++it) {
                const int colb = (wv + 8 * it) * 16 + lrow;
#pragma unroll
                for (int rg = 0; rg < 4; ++rg)
                    sg[lq * 4 + rg][colb] = acc[it][rg];
            }
        }
        __syncthreads();   // B2: sg ready; all sxh reads done -> safe to overwrite sxh

        // ---- pointwise cell update (i,f,g,o); h -> sxh + outputs; x_{t+1} -> sxh ----
#pragma unroll
        for (int p = 0; p < 5; ++p) {
            int e = tid + NT * p;
            int r = e / HP, u = e - r * HP;
            float gi = sg[r][u]          + bcs[u];
            float gf = sg[r][HP + u]     + bcs[HP + u];
            float gg = sg[r][2 * HP + u] + bcs[2 * HP + u];
            float go = sg[r][3 * HP + u] + bcs[3 * HP + u];
            float cn = sigf(gf) * creg[p] + sigf(gi) * tanh_fast(gg);
            creg[p] = cn;
            float h = sigf(go) * tanh_fast(cn);
            sxh[r][HP + u] = bf16_rne(h);
            if (u < 150) {
                outputs[((size_t)t * BATCH + row0 + r) * HD + u] = h;
                if (t == GATED - 1)
                    outh[(size_t)(row0 + r) * HD + u] = h;
            }
        }
        if (pf) {
            { int i = tid;      *(unsigned int*)&sxh[i / 75][2 * (i % 75)] = pk2bf(px0.x, px0.y); }
            { int i = tid + NT; *(unsigned int*)&sxh[i / 75][2 * (i % 75)] = pk2bf(px1.x, px1.y); }
            if (tid + 2 * NT < ROWS * 75) {
                int i = tid + 2 * NT;
                *(unsigned int*)&sxh[i / 75][2 * (i % 75)] = pk2bf(px2.x, px2.y);
            }
        }
        __syncthreads();   // B3: new h + x_{t+1} in sxh
    }

    // =================== post-pass: stop-gate MLP for t < GATED ===================
    // wlds is dead now; stage4/st1p/st2p alias into it.
    for (int i = tid; i < TCH * 16 * SXP; i += NT)
        ((unsigned short*)stage4)[i] = 0;          // zero pads once
    __syncthreads();

    for (int t0 = 0; t0 < GATED; t0 += TCH) {
        const int tcur = (GATED - t0 < TCH) ? (GATED - t0) : TCH;

        // ---- stage [x_t | h_t] as bf16 into stage4 (pads already 0) ----
        for (int i = tid; i < tcur * 16 * 75; i += NT) {
            int row = i / 75, kk = i - row * 75;
            int r = row & 15, tl = row >> 4;
            size_t base = ((size_t)(t0 + tl) * BATCH + row0 + r) * (size_t)XD;
            float2 xv = *(const float2*)(x + base + 2 * kk);
            float2 hv = *(const float2*)(outputs + base + 2 * kk);   // HD==XD
            *(unsigned int*)&stage4[row][2 * kk]      = pk2bf(xv.x, xv.y);
            *(unsigned int*)&stage4[row][HP + 2 * kk] = pk2bf(hv.x, hv.y);
        }
        __syncthreads();

        // ---- w1 MFMAs: 16 jobs (tl, ct), 2 per wave, full K=320 each ----
#pragma unroll
        for (int jj = 0; jj < 2; ++jj) {
            int job = wv * 2 + jj;            // 0..15
            int tl = job >> 2, ct = job & 3;
            if (tl < tcur) {
                const unsigned short* wp1 =
                    Wc + (size_t)(640 + ct * 16 + lrow) * PITCHW + lq * 8;
                floatx4 aw = {0.f, 0.f, 0.f, 0.f};
#pragma unroll
                for (int kb = 0; kb < 10; ++kb) {
                    shortx8 a = *(const shortx8*)&stage4[tl * 16 + lrow][kb * 32 + lq * 8];
                    shortx8 b = *(const shortx8*)(wp1 + kb * 32);
                    aw = __builtin_amdgcn_mfma_f32_16x16x32_bf16(a, b, aw, 0, 0, 0);
                }
#pragma unroll
                for (int rg = 0; rg < 4; ++rg)
                    st1p[tl * 16 + lq * 4 + rg][ct * 16 + lrow] = aw[rg];
            }
        }
        __syncthreads();

        // ---- layer1 bias + relu (in place) ----
        for (int e = tid; e < tcur * 16 * 64; e += NT) {
            int s = e >> 6, j = e & 63;
            float v = st1p[s][j] + b1s[j];
            st1p[s][j] = v > 0.0f ? v : 0.0f;
        }
        __syncthreads();

        // ---- layer2: dot-50 + relu ----
        for (int u = tid; u < tcur * 16 * 25; u += NT) {
            int s = u / 25, j = u - s * 25;
            float a = sb2[j];
            const float* w2r = &sw2[j * 50];
#pragma unroll 10
            for (int k2 = 0; k2 < 50; ++k2)
                a = fmaf(w2r[k2], st1p[s][k2], a);
            st2p[s][j] = a > 0.0f ? a : 0.0f;
        }
        __syncthreads();

        // ---- layer3 + relu + softmax(2) ----
        if (tid < tcur * 16) {
            int tl = tid >> 4, r = tid & 15;
            float z0 = sb3[0], z1 = sb3[1];
#pragma unroll
            for (int k2 = 0; k2 < 25; ++k2) {
                z0 = fmaf(sw3[k2],      st2p[tid][k2], z0);
                z1 = fmaf(sw3[25 + k2], st2p[tid][k2], z1);
            }
            z0 = z0 > 0.0f ? z0 : 0.0f;
            z1 = z1 > 0.0f ? z1 : 0.0f;
            float mx = fmaxf(z0, z1);
            float e0 = __expf(z0 - mx), e1 = __expf(z1 - mx);
            float inv = 1.0f / (e0 + e1);
            size_t yb = ((size_t)(t0 + tl) * BATCH + row0 + r) * 2;
            ys[yb]     = e0 * inv;
            ys[yb + 1] = e1 * inv;
        }
        __syncthreads();   // protect stage4/st1p/st2p before next chunk
    }
}

extern "C" void kernel_launch(void* const* d_in, const int* in_sizes, int n_in,
                              void* d_out, int out_size, void* d_ws, size_t ws_size,
                              hipStream_t stream) {
    const float* x    = (const float*)d_in[0];
    const float* w_ih = (const float*)d_in[1];
    const float* w_hh = (const float*)d_in[2];
    const float* b_ih = (const float*)d_in[3];
    const float* b_hh = (const float*)d_in[4];
    const float* w1   = (const float*)d_in[5];
    const float* b1   = (const float*)d_in[6];
    const float* w2   = (const float*)d_in[7];
    const float* b2   = (const float*)d_in[8];
    const float* w3   = (const float*)d_in[9];
    const float* b3   = (const float*)d_in[10];

    float* out = (float*)d_out;
    unsigned short* Wc  = (unsigned short*)d_ws;           // 704*328 bf16
    float*          bcp = (float*)(Wc + WROWS * PITCHW);   // 640

    pack_weights<<<256, 256, 0, stream>>>(w_ih, w_hh, b_ih, b_hh, w1, Wc, bcp);

    lstm_main<<<NBLK, NT, 0, stream>>>(
        x, Wc, bcp, b1, w2, b2, w3, b3,
        out, out + OFF_OUTPUTS, out + OFF_YS);
}

// Round 3
// 321.300 us; speedup vs baseline: 1.7897x; 1.2525x over previous
//
#include <hip/hip_runtime.h>
#include <math.h>

// ---------------- problem constants ----------------
#define TSTEPS 40
#define GATED  30
#define BATCH  4096
#define XD     150
#define HD     150
#define HP     160      // padded hidden/x dim
#define PITCHW 328      // Wc row pitch (bf16 elems, 656 B)
#define SXP    328      // sxh row pitch (bf16 elems)
#define WROWS  704      // 640 gate rows + 64 w1 rows
#define SGP    643      // sg pitch (fp32)
#define ROWS   16       // batch rows per block (MFMA M)
#define NT     512      // 8 waves
#define NBLK   (BATCH / ROWS)  // 256 blocks -> 1 per CU

// post-pass chunking
#define TCH    4        // timesteps per post-pass chunk
#define S1P    66       // st1p pitch (fp32)
#define S2P    27       // st2p pitch (fp32)

// output packing (flat fp32)
#define OFF_OUTPUTS 614400
#define OFF_YS      25190400

typedef float  floatx4 __attribute__((ext_vector_type(4)));
typedef short  shortx8 __attribute__((ext_vector_type(8)));

__device__ __forceinline__ unsigned short bf16_rne(float f) {
    union { float f; unsigned int u; } v; v.f = f;
    unsigned int u = v.u;
    return (unsigned short)((u + 0x7fffu + ((u >> 16) & 1u)) >> 16);
}
__device__ __forceinline__ unsigned int pk2bf(float a, float b) {
    return (unsigned int)bf16_rne(a) | ((unsigned int)bf16_rne(b) << 16);
}
__device__ __forceinline__ float rcp_f(float x) {
    return __builtin_amdgcn_rcpf(x);
}
__device__ __forceinline__ float sigf(float x) {
    return rcp_f(1.0f + __expf(-x));
}
__device__ __forceinline__ float tanh_fast(float x) {
    x = fminf(fmaxf(x, -15.0f), 15.0f);
    float t = __expf(2.0f * x);
    return (t - 1.0f) * rcp_f(t + 1.0f);
}
// raw barrier: LDS-ordering only, leaves global loads/stores in flight
__device__ __forceinline__ void bar_lds() {
    asm volatile("s_waitcnt lgkmcnt(0)\n\ts_barrier" ::: "memory");
}

// ---------------- weight packing (unchanged) ----------------
__global__ void pack_weights(const float* __restrict__ w_ih, const float* __restrict__ w_hh,
                             const float* __restrict__ b_ih, const float* __restrict__ b_hh,
                             const float* __restrict__ w1,
                             unsigned short* __restrict__ Wc, float* __restrict__ bcp) {
    int idx = blockIdx.x * blockDim.x + threadIdx.x;
    int stride = gridDim.x * blockDim.x;
    for (int i = idx; i < WROWS * PITCHW; i += stride) {
        int j = i / PITCHW, k = i - j * PITCHW;
        float v = 0.0f;
        if (j < 640) {
            int tp = j / HP, u = j - tp * HP;
            if (u < 150) {
                int src = tp * 150 + u;
                if (k < 150)                    v = w_ih[src * 150 + k];
                else if (k >= 160 && k < 310)   v = w_hh[src * 150 + (k - 160)];
            }
        } else {
            int j1 = j - 640;
            if (j1 < 50) {
                if (k < 150)                    v = w1[j1 * 300 + 150 + k];   // x part
                else if (k >= 160 && k < 310)   v = w1[j1 * 300 + (k - 160)]; // h part
            }
        }
        Wc[i] = bf16_rne(v);
    }
    for (int i = idx; i < 640; i += stride) {
        int tp = i / HP, u = i - tp * HP;
        bcp[i] = (u < 150) ? (b_ih[tp * 150 + u] + b_hh[tp * 150 + u]) : 0.0f;
    }
}

// ---------------- main persistent LSTM kernel ----------------
// Chunk-ownership tiling: wave w owns gate tiles {w,10+w,20+w,30+w} =
// (i,f,g,o) at u-chunk [16w,16w+16) -> pointwise for u<128 runs entirely
// in registers (no sg round-trip). Tiles ==8,9 (mod 10) (u in [128,160))
// are each assigned to one wave via wlds and go through sg as before.
__global__ __launch_bounds__(NT, 2)
void lstm_main(const float* __restrict__ x,
               const unsigned short* __restrict__ Wc,
               const float* __restrict__ bcp, const float* __restrict__ b1,
               const float* __restrict__ w2, const float* __restrict__ b2,
               const float* __restrict__ w3, const float* __restrict__ b3,
               float* __restrict__ outh, float* __restrict__ outputs,
               float* __restrict__ ys) {
    __shared__ unsigned short sxh[ROWS][SXP];      // bf16 [x(0..149)|0|h(160..309)|0]
    __shared__ float sg[ROWS][SGP];                // gate pre-acts (only cols of tiles %10>=8 used)
    __shared__ unsigned short wlds[8][16][SXP];    // per-wave extra tile (84 KB)
    __shared__ float bcs[640], b1s[64];
    __shared__ float sw2[1250], sb2[25], sw3[50], sb3[2];

    // post-pass arrays aliased into wlds (dead after recurrent loop)
    unsigned short (*stage4)[SXP] = (unsigned short(*)[SXP])&wlds[0][0][0];
    float (*st1p)[S1P] = (float(*)[S1P])((char*)&wlds[0][0][0] + 41984);
    float (*st2p)[S2P] = (float(*)[S2P])((char*)&wlds[0][0][0] + 58880);

    const int tid  = threadIdx.x;
    const int lane = tid & 63;
    const int wv   = tid >> 6;     // wave 0..7
    const int lrow = lane & 15;    // tile row
    const int lq   = lane >> 4;    // quad 0..3
    const int row0 = blockIdx.x * ROWS;
    const int ET   = 10 * (wv >> 1) + 8 + (wv & 1);   // this wave's extra tile

    // ---- one-time init ----
    for (int i = tid; i < ROWS * SXP; i += NT) {
        int r = i / SXP, k = i - r * SXP;
        if (k >= 150) sxh[r][k] = 0;   // h=0, pads=0
    }
    // stage x_0
    for (int i = tid; i < ROWS * 75; i += NT) {
        int rr = i / 75, kk = i - rr * 75;
        float2 v = *(const float2*)(x + ((size_t)row0 + rr) * XD + 2 * kk);
        *(unsigned int*)&sxh[rr][2 * kk] = pk2bf(v.x, v.y);
    }
    // copy extra tiles (==8,9 mod 10) into wlds[w]
    for (int i = tid; i < 8 * 16 * 160; i += NT) {
        int w = i / (16 * 160);
        int rem = i - w * (16 * 160);
        int r = rem / 160, k = rem - r * 160;   // k counts uint pairs
        int et = 10 * (w >> 1) + 8 + (w & 1);
        *(unsigned int*)&wlds[w][r][2 * k] =
            *(const unsigned int*)&Wc[(size_t)(et * 16 + r) * PITCHW + 2 * k];
    }
    for (int i = tid; i < 640; i += NT) bcs[i] = bcp[i];
    if (tid < 64) b1s[tid] = (tid < 50) ? b1[tid] : 0.0f;
    for (int i = tid; i < 1250; i += NT) sw2[i] = w2[i];
    if (tid < 25) sb2[tid] = b2[tid];
    if (tid < 50) sw3[tid] = w3[tid];
    if (tid < 2)  sb3[tid] = b3[tid];

    // ---- load this wave's 4 chunk tiles (type j, u-chunk wv) into registers ----
    shortx8 bfr[40];
#pragma unroll
    for (int j = 0; j < 4; ++j) {
        const unsigned short* wp =
            Wc + (size_t)((10 * j + wv) * 16 + lrow) * PITCHW + lq * 8;
#pragma unroll
        for (int kb = 0; kb < 10; ++kb)
            bfr[j * 10 + kb] = *(const shortx8*)(wp + kb * 32);
    }

    __syncthreads();

    // ---- loop-invariant hoists (after bcs is populated) ----
    const int uq = wv * 16 + lrow;                 // this lane's chunk u (<128)
    const float bcq0 = bcs[uq];
    const float bcq1 = bcs[160 + uq];
    const float bcq2 = bcs[320 + uq];
    const float bcq3 = bcs[480 + uq];
    const int ue = 128 + (tid & 31);               // extra-chunk u (128..159)
    const int re = tid >> 5;                       // extra-chunk row
    const float bce0 = bcs[ue];
    const float bce1 = bcs[160 + ue];
    const float bce2 = bcs[320 + ue];
    const float bce3 = bcs[480 + ue];
    // x-prefetch per-thread constants
    const int pr0 = tid / 75,          pk0 = tid % 75;
    const int pr1 = (tid + 512) / 75,  pk1 = (tid + 512) % 75;
    const int pr2 = (tid + 1024) / 75, pk2 = (tid + 1024) % 75;  // valid if tid<176

    float cr[4] = {0.f, 0.f, 0.f, 0.f};
    float ce = 0.f;

    // =================== recurrent loop (2 raw barriers/step) ===================
    for (int t = 0; t < TSTEPS; ++t) {
        // ---- prefetch x_{t+1} into registers (stays in flight across B2) ----
        float2 px0, px1, px2;
        const bool pf = (t + 1 < TSTEPS);
        if (pf) {
            const float* xn = x + ((size_t)(t + 1) * BATCH + row0) * XD;
            px0 = *(const float2*)(xn + pr0 * XD + 2 * pk0);
            px1 = *(const float2*)(xn + pr1 * XD + 2 * pk1);
            if (tid < 176) px2 = *(const float2*)(xn + pr2 * XD + 2 * pk2);
        }

        // ---- gate MFMAs: 4 chunk tiles (regs) + 1 extra tile (wlds) ----
        floatx4 acc[5];
#pragma unroll
        for (int j = 0; j < 5; ++j) acc[j] = (floatx4){0.f, 0.f, 0.f, 0.f};
#pragma unroll
        for (int kb = 0; kb < 10; ++kb) {
            shortx8 a = *(const shortx8*)&sxh[lrow][kb * 32 + lq * 8];
#pragma unroll
            for (int j = 0; j < 4; ++j)
                acc[j] = __builtin_amdgcn_mfma_f32_16x16x32_bf16(
                    a, bfr[j * 10 + kb], acc[j], 0, 0, 0);
            shortx8 b4 = *(const shortx8*)&wlds[wv][lrow][kb * 32 + lq * 8];
            acc[4] = __builtin_amdgcn_mfma_f32_16x16x32_bf16(a, b4, acc[4], 0, 0, 0);
        }
        // only the extra tile's pre-acts go through LDS
        {
            const int colb = ET * 16 + lrow;
#pragma unroll
            for (int rg = 0; rg < 4; ++rg)
                sg[lq * 4 + rg][colb] = acc[4][rg];
        }
        bar_lds();   // B2: sg ready; all sxh reads done -> safe to overwrite sxh

        // ---- chunk pointwise: (i,f,g,o) in registers, u = uq < 128 ----
#pragma unroll
        for (int rg = 0; rg < 4; ++rg) {
            float gi = acc[0][rg] + bcq0;
            float gf = acc[1][rg] + bcq1;
            float gg = acc[2][rg] + bcq2;
            float go = acc[3][rg] + bcq3;
            float cn = sigf(gf) * cr[rg] + sigf(gi) * tanh_fast(gg);
            cr[rg] = cn;
            float h = sigf(go) * tanh_fast(cn);
            int r = lq * 4 + rg;
            sxh[r][HP + uq] = bf16_rne(h);
            outputs[((size_t)t * BATCH + row0 + r) * HD + uq] = h;   // uq<128<150
            if (t == GATED - 1)
                outh[(size_t)(row0 + r) * HD + uq] = h;
        }
        // ---- extra pointwise: u = ue in [128,160), via sg ----
        {
            float gi = sg[re][ue]       + bce0;
            float gf = sg[re][160 + ue] + bce1;
            float gg = sg[re][320 + ue] + bce2;
            float go = sg[re][480 + ue] + bce3;
            float cn = sigf(gf) * ce + sigf(gi) * tanh_fast(gg);
            ce = cn;
            float h = sigf(go) * tanh_fast(cn);
            sxh[re][HP + ue] = bf16_rne(h);
            if (ue < 150) {
                outputs[((size_t)t * BATCH + row0 + re) * HD + ue] = h;
                if (t == GATED - 1)
                    outh[(size_t)(row0 + re) * HD + ue] = h;
            }
        }
        // ---- stage x_{t+1} ----
        if (pf) {
            *(unsigned int*)&sxh[pr0][2 * pk0] = pk2bf(px0.x, px0.y);
            *(unsigned int*)&sxh[pr1][2 * pk1] = pk2bf(px1.x, px1.y);
            if (tid < 176)
                *(unsigned int*)&sxh[pr2][2 * pk2] = pk2bf(px2.x, px2.y);
        }
        bar_lds();   // B3: new h + x_{t+1} in sxh
    }

    // =================== post-pass: stop-gate MLP for t < GATED ===================
    // wlds is dead now; stage4/st1p/st2p alias into it.
    for (int i = tid; i < TCH * 16 * SXP; i += NT)
        ((unsigned short*)stage4)[i] = 0;          // zero pads once
    __syncthreads();   // full drain: outputs stores complete before re-read

    for (int t0 = 0; t0 < GATED; t0 += TCH) {
        const int tcur = (GATED - t0 < TCH) ? (GATED - t0) : TCH;

        // ---- stage [x_t | h_t] as bf16 into stage4 (pads already 0) ----
        for (int i = tid; i < tcur * 16 * 75; i += NT) {
            int row = i / 75, kk = i - row * 75;
            int r = row & 15, tl = row >> 4;
            size_t base = ((size_t)(t0 + tl) * BATCH + row0 + r) * (size_t)XD;
            float2 xv = *(const float2*)(x + base + 2 * kk);
            float2 hv = *(const float2*)(outputs + base + 2 * kk);   // HD==XD
            *(unsigned int*)&stage4[row][2 * kk]      = pk2bf(xv.x, xv.y);
            *(unsigned int*)&stage4[row][HP + 2 * kk] = pk2bf(hv.x, hv.y);
        }
        __syncthreads();

        // ---- w1 MFMAs: 16 jobs (tl, ct), 2 per wave, full K=320 each ----
#pragma unroll
        for (int jj = 0; jj < 2; ++jj) {
            int job = wv * 2 + jj;            // 0..15
            int tl = job >> 2, ct = job & 3;
            if (tl < tcur) {
                const unsigned short* wp1 =
                    Wc + (size_t)(640 + ct * 16 + lrow) * PITCHW + lq * 8;
                floatx4 aw = {0.f, 0.f, 0.f, 0.f};
#pragma unroll
                for (int kb = 0; kb < 10; ++kb) {
                    shortx8 a = *(const shortx8*)&stage4[tl * 16 + lrow][kb * 32 + lq * 8];
                    shortx8 b = *(const shortx8*)(wp1 + kb * 32);
                    aw = __builtin_amdgcn_mfma_f32_16x16x32_bf16(a, b, aw, 0, 0, 0);
                }
#pragma unroll
                for (int rg = 0; rg < 4; ++rg)
                    st1p[tl * 16 + lq * 4 + rg][ct * 16 + lrow] = aw[rg];
            }
        }
        __syncthreads();

        // ---- layer1 bias + relu (in place) ----
        for (int e = tid; e < tcur * 16 * 64; e += NT) {
            int s = e >> 6, j = e & 63;
            float v = st1p[s][j] + b1s[j];
            st1p[s][j] = v > 0.0f ? v : 0.0f;
        }
        __syncthreads();

        // ---- layer2: dot-50 + relu ----
        for (int u = tid; u < tcur * 16 * 25; u += NT) {
            int s = u / 25, j = u - s * 25;
            float a = sb2[j];
            const float* w2r = &sw2[j * 50];
#pragma unroll 10
            for (int k2 = 0; k2 < 50; ++k2)
                a = fmaf(w2r[k2], st1p[s][k2], a);
            st2p[s][j] = a > 0.0f ? a : 0.0f;
        }
        __syncthreads();

        // ---- layer3 + relu + softmax(2) ----
        if (tid < tcur * 16) {
            int tl = tid >> 4, r = tid & 15;
            float z0 = sb3[0], z1 = sb3[1];
#pragma unroll
            for (int k2 = 0; k2 < 25; ++k2) {
                z0 = fmaf(sw3[k2],      st2p[tid][k2], z0);
                z1 = fmaf(sw3[25 + k2], st2p[tid][k2], z1);
            }
            z0 = z0 > 0.0f ? z0 : 0.0f;
            z1 = z1 > 0.0f ? z1 : 0.0f;
            float mx = fmaxf(z0, z1);
            float e0 = __expf(z0 - mx), e1 = __expf(z1 - mx);
            float inv = 1.0f / (e0 + e1);
            size_t yb = ((size_t)(t0 + tl) * BATCH + row0 + r) * 2;
            ys[yb]     = e0 * inv;
            ys[yb + 1] = e1 * inv;
        }
        __syncthreads();   // protect stage4/st1p/st2p before next chunk
    }
}

extern "C" void kernel_launch(void* const* d_in, const int* in_sizes, int n_in,
                              void* d_out, int out_size, void* d_ws, size_t ws_size,
                              hipStream_t stream) {
    const float* x    = (const float*)d_in[0];
    const float* w_ih = (const float*)d_in[1];
    const float* w_hh = (const float*)d_in[2];
    const float* b_ih = (const float*)d_in[3];
    const float* b_hh = (const float*)d_in[4];
    const float* w1   = (const float*)d_in[5];
    const float* b1   = (const float*)d_in[6];
    const float* w2   = (const float*)d_in[7];
    const float* b2   = (const float*)d_in[8];
    const float* w3   = (const float*)d_in[9];
    const float* b3   = (const float*)d_in[10];

    float* out = (float*)d_out;
    unsigned short* Wc  = (unsigned short*)d_ws;           // 704*328 bf16
    float*          bcp = (float*)(Wc + WROWS * PITCHW);   // 640

    pack_weights<<<256, 256, 0, stream>>>(w_ih, w_hh, b_ih, b_hh, w1, Wc, bcp);

    lstm_main<<<NBLK, NT, 0, stream>>>(
        x, Wc, bcp, b1, w2, b2, w3, b3,
        out, out + OFF_OUTPUTS, out + OFF_YS);
}

// Round 4
// 318.916 us; speedup vs baseline: 1.8031x; 1.0075x over previous
//
#include <hip/hip_runtime.h>
#include <math.h>

// ---------------- problem constants ----------------
#define TSTEPS 40
#define GATED  30
#define BATCH  4096
#define XD     150
#define HD     150
#define HP     160      // padded hidden/x dim
#define PITCHW 328      // Wc row pitch (bf16 elems, 656 B)
#define SXP    328      // sxh row pitch (bf16 elems)
#define WROWS  704      // 640 gate rows + 64 w1 rows
#define ROWS   16       // batch rows per block (MFMA M)
#define NT     512      // 8 waves
#define NBLK   (BATCH / ROWS)  // 256 blocks -> 1 per CU

// post-pass chunking
#define TCH    4        // timesteps per post-pass chunk
#define S1P    66       // st1p pitch (fp32)
#define S2P    27       // st2p pitch (fp32)

// output packing (flat fp32)
#define OFF_OUTPUTS 614400
#define OFF_YS      25190400

typedef float  floatx4 __attribute__((ext_vector_type(4)));
typedef short  shortx8 __attribute__((ext_vector_type(8)));

__device__ __forceinline__ unsigned short bf16_rne(float f) {
    union { float f; unsigned int u; } v; v.f = f;
    unsigned int u = v.u;
    return (unsigned short)((u + 0x7fffu + ((u >> 16) & 1u)) >> 16);
}
__device__ __forceinline__ unsigned int pk2bf(float a, float b) {
    return (unsigned int)bf16_rne(a) | ((unsigned int)bf16_rne(b) << 16);
}
__device__ __forceinline__ float rcp_f(float x) {
    return __builtin_amdgcn_rcpf(x);
}
__device__ __forceinline__ float sigf(float x) {
    return rcp_f(1.0f + __expf(-x));
}
__device__ __forceinline__ float tanh_fast(float x) {
    x = fminf(fmaxf(x, -15.0f), 15.0f);
    float t = __expf(2.0f * x);
    return (t - 1.0f) * rcp_f(t + 1.0f);
}
// raw barrier: LDS-ordering only, leaves global loads/stores in flight
__device__ __forceinline__ void bar_lds() {
    asm volatile("s_waitcnt lgkmcnt(0)\n\ts_barrier" ::: "memory");
}

// ---------------- weight packing (unchanged) ----------------
__global__ void pack_weights(const float* __restrict__ w_ih, const float* __restrict__ w_hh,
                             const float* __restrict__ b_ih, const float* __restrict__ b_hh,
                             const float* __restrict__ w1,
                             unsigned short* __restrict__ Wc, float* __restrict__ bcp) {
    int idx = blockIdx.x * blockDim.x + threadIdx.x;
    int stride = gridDim.x * blockDim.x;
    for (int i = idx; i < WROWS * PITCHW; i += stride) {
        int j = i / PITCHW, k = i - j * PITCHW;
        float v = 0.0f;
        if (j < 640) {
            int tp = j / HP, u = j - tp * HP;
            if (u < 150) {
                int src = tp * 150 + u;
                if (k < 150)                    v = w_ih[src * 150 + k];
                else if (k >= 160 && k < 310)   v = w_hh[src * 150 + (k - 160)];
            }
        } else {
            int j1 = j - 640;
            if (j1 < 50) {
                if (k < 150)                    v = w1[j1 * 300 + 150 + k];   // x part
                else if (k >= 160 && k < 310)   v = w1[j1 * 300 + (k - 160)]; // h part
            }
        }
        Wc[i] = bf16_rne(v);
    }
    for (int i = idx; i < 640; i += stride) {
        int tp = i / HP, u = i - tp * HP;
        bcp[i] = (u < 150) ? (b_ih[tp * 150 + u] + b_hh[tp * 150 + u]) : 0.0f;
    }
}

// ---------------- main persistent LSTM kernel ----------------
// Double-buffered sxh: the chunk pointwise (register inputs) runs BEFORE the
// first barrier, overlapping other waves' LDS streaming. Phase 2 is only the
// 32-col extra pointwise via the small sge array.
__global__ __launch_bounds__(NT, 2)
void lstm_main(const float* __restrict__ x,
               const unsigned short* __restrict__ Wc,
               const float* __restrict__ bcp, const float* __restrict__ b1,
               const float* __restrict__ w2, const float* __restrict__ b2,
               const float* __restrict__ w3, const float* __restrict__ b3,
               float* __restrict__ outh, float* __restrict__ outputs,
               float* __restrict__ ys) {
    __shared__ unsigned short sxh[2][ROWS][SXP];   // bf16 [x(0..149)|0|h(160..309)|junk]
    __shared__ float sge[ROWS][4][33];             // extra-chunk pre-acts (type, col 0..31)
    __shared__ unsigned short wlds[8][16][SXP];    // per-wave extra tile (84 KB)
    __shared__ float bcs[640], b1s[64];
    __shared__ float sw2[1250], sb2[25], sw3[50], sb3[2];

    // post-pass arrays aliased into wlds (dead after recurrent loop)
    unsigned short (*stage4)[SXP] = (unsigned short(*)[SXP])&wlds[0][0][0];
    float (*st1p)[S1P] = (float(*)[S1P])((char*)&wlds[0][0][0] + 41984);
    float (*st2p)[S2P] = (float(*)[S2P])((char*)&wlds[0][0][0] + 58880);

    const int tid  = threadIdx.x;
    const int lane = tid & 63;
    const int wv   = tid >> 6;     // wave 0..7
    const int lrow = lane & 15;    // tile row
    const int lq   = lane >> 4;    // quad 0..3
    const int row0 = blockIdx.x * ROWS;
    const int ty   = wv >> 1;      // extra-tile type 0..3
    const int ch   = wv & 1;       // extra-tile col half

    // ---- one-time init ----
    for (int i = tid; i < 2 * ROWS * SXP; i += NT) {
        int b = i / (ROWS * SXP);
        int rem = i - b * (ROWS * SXP);
        int r = rem / SXP, k = rem - r * SXP;
        if (k >= 150) sxh[b][r][k] = 0;   // h0=0, pads=0
    }
    // stage x_0 into buffer 0
    for (int i = tid; i < ROWS * 75; i += NT) {
        int rr = i / 75, kk = i - rr * 75;
        float2 v = *(const float2*)(x + ((size_t)row0 + rr) * XD + 2 * kk);
        *(unsigned int*)&sxh[0][rr][2 * kk] = pk2bf(v.x, v.y);
    }
    // copy extra tiles (==8,9 mod 10) into wlds[w]
    for (int i = tid; i < 8 * 16 * 160; i += NT) {
        int w = i / (16 * 160);
        int rem = i - w * (16 * 160);
        int r = rem / 160, k = rem - r * 160;   // k counts uint pairs
        int et = 10 * (w >> 1) + 8 + (w & 1);
        *(unsigned int*)&wlds[w][r][2 * k] =
            *(const unsigned int*)&Wc[(size_t)(et * 16 + r) * PITCHW + 2 * k];
    }
    for (int i = tid; i < 640; i += NT) bcs[i] = bcp[i];
    if (tid < 64) b1s[tid] = (tid < 50) ? b1[tid] : 0.0f;
    for (int i = tid; i < 1250; i += NT) sw2[i] = w2[i];
    if (tid < 25) sb2[tid] = b2[tid];
    if (tid < 50) sw3[tid] = w3[tid];
    if (tid < 2)  sb3[tid] = b3[tid];

    // ---- load this wave's 4 chunk tiles (type j, u-chunk wv) into registers ----
    shortx8 bfr[40];
#pragma unroll
    for (int j = 0; j < 4; ++j) {
        const unsigned short* wp =
            Wc + (size_t)((10 * j + wv) * 16 + lrow) * PITCHW + lq * 8;
#pragma unroll
        for (int kb = 0; kb < 10; ++kb)
            bfr[j * 10 + kb] = *(const shortx8*)(wp + kb * 32);
    }

    __syncthreads();

    // ---- loop-invariant hoists ----
    const int uq = wv * 16 + lrow;                 // this lane's chunk u (<128)
    const float bcq0 = bcs[uq];
    const float bcq1 = bcs[160 + uq];
    const float bcq2 = bcs[320 + uq];
    const float bcq3 = bcs[480 + uq];
    const int ce_c = tid & 31;                     // extra col 0..31
    const int ue = 128 + ce_c;                     // extra u (128..159)
    const int re = tid >> 5;                       // extra row 0..15
    const float bce0 = bcs[ue];
    const float bce1 = bcs[160 + ue];
    const float bce2 = bcs[320 + ue];
    const float bce3 = bcs[480 + ue];
    // x-prefetch per-thread constants
    const int pr0 = tid / 75,          pk0 = tid % 75;
    const int pr1 = (tid + 512) / 75,  pk1 = (tid + 512) % 75;
    const int pr2 = (tid + 1024) / 75, pk2 = (tid + 1024) % 75;  // valid if tid<176

    // incremental output pointers
    float* outc = outputs + (size_t)(row0 + lq * 4) * HD + uq;   // rows lq*4+rg
    float* oute = outputs + (size_t)(row0 + re) * HD + ue;       // extra

    float cr[4] = {0.f, 0.f, 0.f, 0.f};
    float cex = 0.f;

    unsigned short (*sxc)[SXP] = sxh[0];
    unsigned short (*sxn)[SXP] = sxh[1];

    // =================== recurrent loop ===================
    for (int t = 0; t < TSTEPS; ++t) {
        // ---- prefetch x_{t+1} into registers (stays in flight) ----
        float2 px0, px1, px2;
        const bool pf = (t + 1 < TSTEPS);
        if (pf) {
            const float* xn = x + ((size_t)(t + 1) * BATCH + row0) * XD;
            px0 = *(const float2*)(xn + pr0 * XD + 2 * pk0);
            px1 = *(const float2*)(xn + pr1 * XD + 2 * pk1);
            if (tid < 176) px2 = *(const float2*)(xn + pr2 * XD + 2 * pk2);
        }

        // ---- gate MFMAs: 4 chunk tiles (regs) + 1 extra tile (wlds) ----
        floatx4 acc[5];
#pragma unroll
        for (int j = 0; j < 5; ++j) acc[j] = (floatx4){0.f, 0.f, 0.f, 0.f};
#pragma unroll
        for (int kb = 0; kb < 10; ++kb) {
            shortx8 a = *(const shortx8*)&sxc[lrow][kb * 32 + lq * 8];
#pragma unroll
            for (int j = 0; j < 4; ++j)
                acc[j] = __builtin_amdgcn_mfma_f32_16x16x32_bf16(
                    a, bfr[j * 10 + kb], acc[j], 0, 0, 0);
            shortx8 b4 = *(const shortx8*)&wlds[wv][lrow][kb * 32 + lq * 8];
            acc[4] = __builtin_amdgcn_mfma_f32_16x16x32_bf16(a, b4, acc[4], 0, 0, 0);
        }
        // extra-tile pre-acts -> sge (small)
#pragma unroll
        for (int rg = 0; rg < 4; ++rg)
            sge[lq * 4 + rg][ty][ch * 16 + lrow] = acc[4][rg];

        // ---- chunk pointwise (register inputs) -> sxn + outputs ----
        // overlaps other waves' LDS streaming; no barrier needed before this
#pragma unroll
        for (int rg = 0; rg < 4; ++rg) {
            float gi = acc[0][rg] + bcq0;
            float gf = acc[1][rg] + bcq1;
            float gg = acc[2][rg] + bcq2;
            float go = acc[3][rg] + bcq3;
            float cn = sigf(gf) * cr[rg] + sigf(gi) * tanh_fast(gg);
            cr[rg] = cn;
            float h = sigf(go) * tanh_fast(cn);
            sxn[lq * 4 + rg][HP + uq] = bf16_rne(h);
            outc[rg * HD] = h;                       // uq<128<150 always valid
            if (t == GATED - 1)
                outh[(size_t)(row0 + lq * 4 + rg) * HD + uq] = h;
        }
        // ---- stage x_{t+1} into sxn ----
        if (pf) {
            *(unsigned int*)&sxn[pr0][2 * pk0] = pk2bf(px0.x, px0.y);
            *(unsigned int*)&sxn[pr1][2 * pk1] = pk2bf(px1.x, px1.y);
            if (tid < 176)
                *(unsigned int*)&sxn[pr2][2 * pk2] = pk2bf(px2.x, px2.y);
        }
        bar_lds();   // B1: sge visible; all sxc reads done

        // ---- extra pointwise: u in [128,160), via sge ----
        {
            float gi = sge[re][0][ce_c] + bce0;
            float gf = sge[re][1][ce_c] + bce1;
            float gg = sge[re][2][ce_c] + bce2;
            float go = sge[re][3][ce_c] + bce3;
            float cn = sigf(gf) * cex + sigf(gi) * tanh_fast(gg);
            cex = cn;
            float h = sigf(go) * tanh_fast(cn);
            sxn[re][HP + ue] = bf16_rne(h);
            if (ue < 150) {
                oute[0] = h;
                if (t == GATED - 1)
                    outh[(size_t)(row0 + re) * HD + ue] = h;
            }
        }
        bar_lds();   // B2: sxn complete (h chunk + h extra + x_{t+1})

        // swap buffers, advance output pointers
        { unsigned short (*tmp)[SXP] = sxc; sxc = sxn; sxn = tmp; }
        outc += (size_t)BATCH * HD;
        oute += (size_t)BATCH * HD;
    }

    // =================== post-pass: stop-gate MLP for t < GATED ===================
    // wlds is dead now; stage4/st1p/st2p alias into it.
    for (int i = tid; i < TCH * 16 * SXP; i += NT)
        ((unsigned short*)stage4)[i] = 0;          // zero pads once
    __syncthreads();   // full drain: outputs stores complete before re-read

    for (int t0 = 0; t0 < GATED; t0 += TCH) {
        const int tcur = (GATED - t0 < TCH) ? (GATED - t0) : TCH;

        // ---- stage [x_t | h_t] as bf16 into stage4 (pads already 0) ----
        for (int i = tid; i < tcur * 16 * 75; i += NT) {
            int row = i / 75, kk = i - row * 75;
            int r = row & 15, tl = row >> 4;
            size_t base = ((size_t)(t0 + tl) * BATCH + row0 + r) * (size_t)XD;
            float2 xv = *(const float2*)(x + base + 2 * kk);
            float2 hv = *(const float2*)(outputs + base + 2 * kk);   // HD==XD
            *(unsigned int*)&stage4[row][2 * kk]      = pk2bf(xv.x, xv.y);
            *(unsigned int*)&stage4[row][HP + 2 * kk] = pk2bf(hv.x, hv.y);
        }
        __syncthreads();

        // ---- w1 MFMAs: 16 jobs (tl, ct), 2 per wave, full K=320 each ----
#pragma unroll
        for (int jj = 0; jj < 2; ++jj) {
            int job = wv * 2 + jj;            // 0..15
            int tl = job >> 2, ct = job & 3;
            if (tl < tcur) {
                const unsigned short* wp1 =
                    Wc + (size_t)(640 + ct * 16 + lrow) * PITCHW + lq * 8;
                floatx4 aw = {0.f, 0.f, 0.f, 0.f};
#pragma unroll
                for (int kb = 0; kb < 10; ++kb) {
                    shortx8 a = *(const shortx8*)&stage4[tl * 16 + lrow][kb * 32 + lq * 8];
                    shortx8 b = *(const shortx8*)(wp1 + kb * 32);
                    aw = __builtin_amdgcn_mfma_f32_16x16x32_bf16(a, b, aw, 0, 0, 0);
                }
#pragma unroll
                for (int rg = 0; rg < 4; ++rg)
                    st1p[tl * 16 + lq * 4 + rg][ct * 16 + lrow] = aw[rg];
            }
        }
        __syncthreads();

        // ---- layer1 bias + relu (in place) ----
        for (int e = tid; e < tcur * 16 * 64; e += NT) {
            int s = e >> 6, j = e & 63;
            float v = st1p[s][j] + b1s[j];
            st1p[s][j] = v > 0.0f ? v : 0.0f;
        }
        __syncthreads();

        // ---- layer2: dot-50 + relu ----
        for (int u = tid; u < tcur * 16 * 25; u += NT) {
            int s = u / 25, j = u - s * 25;
            float a = sb2[j];
            const float* w2r = &sw2[j * 50];
#pragma unroll 10
            for (int k2 = 0; k2 < 50; ++k2)
                a = fmaf(w2r[k2], st1p[s][k2], a);
            st2p[s][j] = a > 0.0f ? a : 0.0f;
        }
        __syncthreads();

        // ---- layer3 + relu + softmax(2) ----
        if (tid < tcur * 16) {
            int tl = tid >> 4, r = tid & 15;
            float z0 = sb3[0], z1 = sb3[1];
#pragma unroll
            for (int k2 = 0; k2 < 25; ++k2) {
                z0 = fmaf(sw3[k2],      st2p[tid][k2], z0);
                z1 = fmaf(sw3[25 + k2], st2p[tid][k2], z1);
            }
            z0 = z0 > 0.0f ? z0 : 0.0f;
            z1 = z1 > 0.0f ? z1 : 0.0f;
            float mx = fmaxf(z0, z1);
            float e0 = __expf(z0 - mx), e1 = __expf(z1 - mx);
            float inv = 1.0f / (e0 + e1);
            size_t yb = ((size_t)(t0 + tl) * BATCH + row0 + r) * 2;
            ys[yb]     = e0 * inv;
            ys[yb + 1] = e1 * inv;
        }
        __syncthreads();   // protect stage4/st1p/st2p before next chunk
    }
}

extern "C" void kernel_launch(void* const* d_in, const int* in_sizes, int n_in,
                              void* d_out, int out_size, void* d_ws, size_t ws_size,
                              hipStream_t stream) {
    const float* x    = (const float*)d_in[0];
    const float* w_ih = (const float*)d_in[1];
    const float* w_hh = (const float*)d_in[2];
    const float* b_ih = (const float*)d_in[3];
    const float* b_hh = (const float*)d_in[4];
    const float* w1   = (const float*)d_in[5];
    const float* b1   = (const float*)d_in[6];
    const float* w2   = (const float*)d_in[7];
    const float* b2   = (const float*)d_in[8];
    const float* w3   = (const float*)d_in[9];
    const float* b3   = (const float*)d_in[10];

    float* out = (float*)d_out;
    unsigned short* Wc  = (unsigned short*)d_ws;           // 704*328 bf16
    float*          bcp = (float*)(Wc + WROWS * PITCHW);   // 640

    pack_weights<<<256, 256, 0, stream>>>(w_ih, w_hh, b_ih, b_hh, w1, Wc, bcp);

    lstm_main<<<NBLK, NT, 0, stream>>>(
        x, Wc, bcp, b1, w2, b2, w3, b3,
        out, out + OFF_OUTPUTS, out + OFF_YS);
}